// Round 1
// baseline (442.794 us; speedup 1.0000x reference)
//
#include <hip/hip_runtime.h>
#include <hip/hip_bf16.h>
#include <math.h>

#define N 8192
#define D 512
#define BM 128
#define BN 128
#define BK 64
#define NHALF 4096
#define NTILES (NHALF / BN) // 32
#define KCH (D / BK)        // 8

typedef __bf16 bf16x8 __attribute__((ext_vector_type(8)));
typedef float f32x4 __attribute__((ext_vector_type(4)));

__device__ inline void gload_lds16(const void* g, void* l) {
  __builtin_amdgcn_global_load_lds(
      (const __attribute__((address_space(1))) void*)g,
      (__attribute__((address_space(3))) void*)l, 16, 0, 0);
}

// ---------------- normalize + exact fp32 diagonal ----------------
__global__ __launch_bounds__(256) void norm_kernel(
    const float* __restrict__ z1, const float* __restrict__ z2,
    ushort* __restrict__ zn1, ushort* __restrict__ zn2, float* __restrict__ diag) {
  int row = blockIdx.x;
  int t = threadIdx.x;
  const float* a = z1 + (size_t)row * D;
  const float* b = z2 + (size_t)row * D;
  float va[2], vb[2];
  float ss1 = 0.f, ss2 = 0.f, dd = 0.f;
#pragma unroll
  for (int i = 0; i < 2; i++) {
    float x = a[t + 256 * i];
    float y = b[t + 256 * i];
    va[i] = x; vb[i] = y;
    ss1 += x * x; ss2 += y * y; dd += x * y;
  }
#pragma unroll
  for (int off = 1; off < 64; off <<= 1) {
    ss1 += __shfl_xor(ss1, off);
    ss2 += __shfl_xor(ss2, off);
    dd  += __shfl_xor(dd,  off);
  }
  __shared__ float red[3][4];
  int wv = t >> 6;
  if ((t & 63) == 0) { red[0][wv] = ss1; red[1][wv] = ss2; red[2][wv] = dd; }
  __syncthreads();
  ss1 = red[0][0] + red[0][1] + red[0][2] + red[0][3];
  ss2 = red[1][0] + red[1][1] + red[1][2] + red[1][3];
  dd  = red[2][0] + red[2][1] + red[2][2] + red[2][3];
  float i1 = 1.0f / fmaxf(sqrtf(ss1), 1e-12f);
  float i2 = 1.0f / fmaxf(sqrtf(ss2), 1e-12f);
#pragma unroll
  for (int i = 0; i < 2; i++) {
    __bf16 c1 = (__bf16)(va[i] * i1);
    __bf16 c2 = (__bf16)(vb[i] * i2);
    zn1[(size_t)row * D + t + 256 * i] = *(ushort*)&c1;
    zn2[(size_t)row * D + t + 256 * i] = *(ushort*)&c2;
  }
  if (t == 0) diag[row] = dd * i1 * i2;
}

// ---------------- fused strip GEMM + online LSE / masked row-max ----------------
// grid: 512 blocks = pass(4) x strip(64) x half(2). 256 threads = 4 waves,
// each wave owns a 64x64 quadrant of the 128x128 tile (m97 structure).
__global__ __launch_bounds__(256) void strip_kernel(
    const ushort* __restrict__ zn1, const ushort* __restrict__ zn2,
    float* __restrict__ l12m, float* __restrict__ l12s,
    float* __restrict__ l21m, float* __restrict__ l21s,
    float* __restrict__ mx1, float* __restrict__ mx2) {
  int bx = blockIdx.x;
  int half = bx & 1;
  int strip = (bx >> 1) & 63;
  int pass = bx >> 7;

  const ushort* X; const ushort* Y;
  float* om; float* os;
  int mode; // 0 = LSE, 1 = masked max
  if (pass == 0)      { X = zn1; Y = zn2; mode = 0; om = l12m; os = l12s; }
  else if (pass == 1) { X = zn2; Y = zn1; mode = 0; om = l21m; os = l21s; }
  else if (pass == 2) { X = zn1; Y = zn1; mode = 1; om = mx1;  os = nullptr; }
  else                { X = zn2; Y = zn2; mode = 1; om = mx2;  os = nullptr; }

  const int r0 = strip * BM;
  const int c0 = half * NHALF;
  // logits scale folded with log2(e) so we can use native exp2
  const float scale = 1.4426950408889634f / 0.04f;

  __shared__ ushort At[BM * BK]; // 16 KB, xor-swizzled 16B slots
  __shared__ ushort Bt[BN * BK]; // 16 KB
  __shared__ float redm[2][BM];
  __shared__ float reds[2][BM];
  __shared__ float stm[BM];
  __shared__ float sts[BM];

  int t = threadIdx.x;
  int lane = t & 63;
  int wave = t >> 6;
  int quad = lane >> 4;
  int lr = lane & 15;
  int rw = wave >> 1; // wave row half (0/1)
  int cw = wave & 1;  // wave col half (0/1)

  if (t < BM) { stm[t] = -3.0e38f; sts[t] = 0.0f; }

  const f32x4 vzero = {0.0f, 0.0f, 0.0f, 0.0f};

  for (int nt = 0; nt < NTILES; nt++) {
    int n0 = c0 + nt * BN;
    f32x4 acc[4][4];
#pragma unroll
    for (int i = 0; i < 4; i++)
#pragma unroll
      for (int j = 0; j < 4; j++) acc[i][j] = vzero;

    for (int kc = 0; kc < KCH; kc++) {
      int k0 = kc * BK;
      __syncthreads(); // LDS reuse guard (also orders epilogue vs restage)
      // stage A tile: 1024 16B slots, lane-contiguous LDS (global_load_lds req.)
#pragma unroll
      for (int it = 0; it < 4; it++) {
        int s = it * 256 + t;
        int row = s >> 3, cs = s & 7;
        int src = cs ^ (row & 7); // xor swizzle: LDS[row][cs] = X[row][(cs^row7)*8..]
        gload_lds16(X + (size_t)(r0 + row) * D + k0 + src * 8, &At[s * 8]);
      }
#pragma unroll
      for (int it = 0; it < 4; it++) {
        int s = it * 256 + t;
        int row = s >> 3, cs = s & 7;
        int src = cs ^ (row & 7);
        gload_lds16(Y + (size_t)(n0 + row) * D + k0 + src * 8, &Bt[s * 8]);
      }
      __syncthreads(); // barrier drains vmcnt -> tiles ready
#pragma unroll
      for (int ks = 0; ks < 2; ks++) {
        bf16x8 af[4], bfr[4];
#pragma unroll
        for (int i = 0; i < 4; i++) {
          int row = rw * 64 + i * 16 + lr;
          int slot = (ks * 4 + quad) ^ (row & 7);
          af[i] = *(const bf16x8*)&At[row * BK + slot * 8];
        }
#pragma unroll
        for (int j = 0; j < 4; j++) {
          int row = cw * 64 + j * 16 + lr;
          int slot = (ks * 4 + quad) ^ (row & 7);
          bfr[j] = *(const bf16x8*)&Bt[row * BK + slot * 8];
        }
#pragma unroll
        for (int i = 0; i < 4; i++)
#pragma unroll
          for (int j = 0; j < 4; j++)
            acc[i][j] = __builtin_amdgcn_mfma_f32_16x16x32_bf16(af[i], bfr[j], acc[i][j], 0, 0, 0);
      }
    }

    // ---- epilogue for this 128x128 tile ----
    if (mode == 0) {
      // 1) per-row tile max (raw G units; scale>0 commutes with max)
      float lmax[4][4];
#pragma unroll
      for (int i = 0; i < 4; i++)
#pragma unroll
        for (int r = 0; r < 4; r++) {
          float v = fmaxf(fmaxf(acc[i][0][r], acc[i][1][r]),
                          fmaxf(acc[i][2][r], acc[i][3][r]));
#pragma unroll
          for (int off = 1; off < 16; off <<= 1) v = fmaxf(v, __shfl_xor(v, off));
          lmax[i][r] = v;
        }
      if (lr == 0) {
#pragma unroll
        for (int i = 0; i < 4; i++)
#pragma unroll
          for (int r = 0; r < 4; r++)
            redm[cw][rw * 64 + i * 16 + quad * 4 + r] = lmax[i][r];
      }
      __syncthreads();
      // 2) merge running max, rescale running sum (one thread per row)
      if (t < BM) {
        float tm = fmaxf(redm[0][t], redm[1][t]) * scale;
        float mo = stm[t];
        float mn = fmaxf(mo, tm);
        stm[t] = mn;
        sts[t] = sts[t] * __builtin_amdgcn_exp2f(mo - mn);
      }
      __syncthreads();
      // 3) sum exp2(scale*g - m) over this tile's 128 cols
      float lsum[4][4];
#pragma unroll
      for (int i = 0; i < 4; i++)
#pragma unroll
        for (int r = 0; r < 4; r++) {
          float mrow = stm[rw * 64 + i * 16 + quad * 4 + r];
          float s = 0.0f;
#pragma unroll
          for (int j = 0; j < 4; j++)
            s += __builtin_amdgcn_exp2f(fmaf(acc[i][j][r], scale, -mrow));
#pragma unroll
          for (int off = 1; off < 16; off <<= 1) s += __shfl_xor(s, off);
          lsum[i][r] = s;
        }
      if (lr == 0) {
#pragma unroll
        for (int i = 0; i < 4; i++)
#pragma unroll
          for (int r = 0; r < 4; r++)
            reds[cw][rw * 64 + i * 16 + quad * 4 + r] = lsum[i][r];
      }
      __syncthreads();
      if (t < BM) sts[t] += reds[0][t] + reds[1][t];
      // next-tile k-loop barrier guards reds reuse
    } else {
      // masked row-max (exclude diagonal)
      float lmax[4][4];
#pragma unroll
      for (int i = 0; i < 4; i++)
#pragma unroll
        for (int r = 0; r < 4; r++) {
          int gr = r0 + rw * 64 + i * 16 + quad * 4 + r;
          float v = -3.0e38f;
#pragma unroll
          for (int j = 0; j < 4; j++) {
            float x = acc[i][j][r];
            int gc = n0 + cw * 64 + j * 16 + lr;
            if (gc == gr) x = -3.0e38f;
            v = fmaxf(v, x);
          }
#pragma unroll
          for (int off = 1; off < 16; off <<= 1) v = fmaxf(v, __shfl_xor(v, off));
          lmax[i][r] = v;
        }
      if (lr == 0) {
#pragma unroll
        for (int i = 0; i < 4; i++)
#pragma unroll
          for (int r = 0; r < 4; r++)
            redm[cw][rw * 64 + i * 16 + quad * 4 + r] = lmax[i][r];
      }
      __syncthreads();
      if (t < BM) stm[t] = fmaxf(stm[t], fmaxf(redm[0][t], redm[1][t]));
      // next-tile k-loop barrier guards redm reuse
    }
  }

  __syncthreads();
  if (t < BM) {
    int gr = r0 + t;
    om[half * N + gr] = stm[t];
    if (mode == 0) os[half * N + gr] = sts[t];
  }
}

// ---------------- final scalar reduction ----------------
__global__ __launch_bounds__(256) void finalize_kernel(
    const float* __restrict__ diag,
    const float* __restrict__ l12m, const float* __restrict__ l12s,
    const float* __restrict__ l21m, const float* __restrict__ l21s,
    const float* __restrict__ mx1, const float* __restrict__ mx2,
    float* __restrict__ out) {
  const float invT = 25.0f;
  const float ln2 = 0.6931471805599453f;
  float a12 = 0.f, a21 = 0.f, k1 = 0.f, k2 = 0.f;
  for (int i = threadIdx.x; i < N; i += 256) {
    float m0 = l12m[i], m1 = l12m[N + i], s0 = l12s[i], s1 = l12s[N + i];
    float M = fmaxf(m0, m1);
    float S = s0 * exp2f(m0 - M) + s1 * exp2f(m1 - M);
    a12 += ln2 * (M + log2f(S)) - diag[i] * invT;

    m0 = l21m[i]; m1 = l21m[N + i]; s0 = l21s[i]; s1 = l21s[N + i];
    M = fmaxf(m0, m1);
    S = s0 * exp2f(m0 - M) + s1 * exp2f(m1 - M);
    a21 += ln2 * (M + log2f(S)) - diag[i] * invT;

    float g1 = fmaxf(mx1[i], mx1[N + i]);
    float g2 = fmaxf(mx2[i], mx2[N + i]);
    float d1 = sqrtf(fmaxf(2.0f - 2.0f * g1, 0.0f));
    float d2 = sqrtf(fmaxf(2.0f - 2.0f * g2, 0.0f));
    k1 += logf(d1 + 1e-9f);
    k2 += logf(d2 + 1e-9f);
  }
#pragma unroll
  for (int off = 1; off < 64; off <<= 1) {
    a12 += __shfl_xor(a12, off);
    a21 += __shfl_xor(a21, off);
    k1  += __shfl_xor(k1,  off);
    k2  += __shfl_xor(k2,  off);
  }
  __shared__ float fr[4][4];
  int wv = threadIdx.x >> 6;
  if ((threadIdx.x & 63) == 0) { fr[0][wv] = a12; fr[1][wv] = a21; fr[2][wv] = k1; fr[3][wv] = k2; }
  __syncthreads();
  if (threadIdx.x == 0) {
    a12 = fr[0][0] + fr[0][1] + fr[0][2] + fr[0][3];
    a21 = fr[1][0] + fr[1][1] + fr[1][2] + fr[1][3];
    k1  = fr[2][0] + fr[2][1] + fr[2][2] + fr[2][3];
    k2  = fr[3][0] + fr[3][1] + fr[3][2] + fr[3][3];
    float contrastive = 0.5f * (a12 + a21) / (float)N;
    float koleo = -0.5f * (k1 + k2) / (float)N;
    out[0] = contrastive + 0.1f * koleo;
  }
}

extern "C" void kernel_launch(void* const* d_in, const int* in_sizes, int n_in,
                              void* d_out, int out_size, void* d_ws, size_t ws_size,
                              hipStream_t stream) {
  const float* z1 = (const float*)d_in[0];
  const float* z2 = (const float*)d_in[1];
  char* w = (char*)d_ws;
  ushort* zn1 = (ushort*)w;          w += (size_t)N * D * sizeof(ushort);
  ushort* zn2 = (ushort*)w;          w += (size_t)N * D * sizeof(ushort);
  float* diag = (float*)w;           w += (size_t)N * sizeof(float);
  float* l12m = (float*)w;           w += (size_t)2 * N * sizeof(float);
  float* l12s = (float*)w;           w += (size_t)2 * N * sizeof(float);
  float* l21m = (float*)w;           w += (size_t)2 * N * sizeof(float);
  float* l21s = (float*)w;           w += (size_t)2 * N * sizeof(float);
  float* mx1  = (float*)w;           w += (size_t)2 * N * sizeof(float);
  float* mx2  = (float*)w;           w += (size_t)2 * N * sizeof(float);
  float* out  = (float*)d_out;

  norm_kernel<<<N, 256, 0, stream>>>(z1, z2, zn1, zn2, diag);
  strip_kernel<<<512, 256, 0, stream>>>(zn1, zn2, l12m, l12s, l21m, l21s, mx1, mx2);
  finalize_kernel<<<1, 256, 0, stream>>>(diag, l12m, l12s, l21m, l21s, mx1, mx2, out);
}